// Round 10
// baseline (86.056 us; speedup 1.0000x reference)
//
#include <hip/hip_runtime.h>

// B=16, C=3, H=256, W=256 fp32. 48 slices of 256x256.
// out = inverted, per-slice max-normalized, per-channel-weighted exact EDT.
//
// Pipeline (2 app launches; kernel boundary is the only global sync —
// measured: atomic-spin ~50us, coop grid.sync ~120us, boundary ~5us):
//   KF: 768 blocks = 48 slices x 16 row-slabs. Block covers rows
//       r0-16..r0+31 (48) x all 256 cols, SELF-CONTAINED:
//       Phase A: each wave ballot-EDTs 12 rows (exact 1D nearest-zero dist
//                per lane's 4 cols, register-only residue prefix max/min),
//                writes d^2 f32 into LDS [48][260] (49.9 KB, 3 blk/CU).
//       Phase B: one column/thread: own[16]+lo[16]+hi[16] regs; +-16 paired
//                window min-plus; EXACT fallback (brute-force whole input
//                slice) when windowed min > 288 (|o|>=17 candidates >= 289;
//                needs a 33x33 zero-free region -> never taken, execz).
//       Writes d2 -> out (coalesced full rows), slab max -> ws.
//   K3: slice max = reduce 16 slab maxes; out = (mx - w*sqrt(d2))/mx.
// No global g buffer: input rows re-read 3x (~37 MB, ~6us) instead of a
// K1 dispatch + 12.6 MB g round trip (~10us).

#define PADV 1e30f

// ---------------- KF: fused g + column min-plus -----------------------------
__global__ __launch_bounds__(256) __attribute__((amdgpu_waves_per_eu(3)))
void kfused(const float* __restrict__ in,
            float* __restrict__ d2out,
            float* __restrict__ slabmax) {
    __shared__ __align__(16) float tile[48 * 260];   // 49920 B
    __shared__ float wm[4];
    int bx = blockIdx.x;
    int slice = bx >> 4;
    int slab = bx & 15;
    int r0 = slab * 16;                // owned rows r0..r0+15 (slice-local)
    int tid = threadIdx.x;
    int lane = tid & 63;
    int wv = tid >> 6;                 // 0..3

    // ---- phase A: ballot-EDT for rows r0-16 .. r0+31 into LDS --------------
    // Lane l holds cols 4l..4l+3. b[cc] bit j = (col 4j+cc == 0).
    {
        unsigned long long loP = ~0ull >> (63 - lane);  // bits 0..lane
        unsigned long long loM = loP >> 1;              // bits 0..lane-1
        unsigned long long hiP = ~0ull << lane;         // bits lane..63
        unsigned long long hiM = hiP << 1;              // bits lane+1..63
        #pragma unroll
        for (int i = 0; i < 12; ++i) {
            int ti = wv * 12 + i;      // tile row 0..47
            int r = r0 - 16 + ti;      // slice-local row
            float4 res;
            if (r >= 0 && r < 256) {
                const float4 m = ((const float4*)(in + (long)slice * 65536 + (long)r * 256))[lane];
                unsigned long long b[4];
                b[0] = __ballot(m.x == 0.f);
                b[1] = __ballot(m.y == 0.f);
                b[2] = __ballot(m.z == 0.f);
                b[3] = __ballot(m.w == 0.f);

                int LP[4], LM[4], RP[4], RM[4];
                #pragma unroll
                for (int cc = 0; cc < 4; ++cc) {
                    unsigned long long mlp = b[cc] & loP;
                    unsigned long long mlm = b[cc] & loM;
                    unsigned long long mhp = b[cc] & hiP;
                    unsigned long long mhm = b[cc] & hiM;
                    LP[cc] = mlp ? 4 * (63 - __builtin_clzll(mlp)) + cc : -1000;
                    LM[cc] = mlm ? 4 * (63 - __builtin_clzll(mlm)) + cc : -1000;
                    RP[cc] = mhp ? 4 * __builtin_ctzll(mhp) + cc : 2000;
                    RM[cc] = mhm ? 4 * __builtin_ctzll(mhm) + cc : 2000;
                }
                // colL(ci) = max( LP[cc] for cc<=ci, LM[cc] for cc>ci )
                int qp1 = max(LP[0], LP[1]);
                int qp2 = max(qp1, LP[2]);
                int qp3 = max(qp2, LP[3]);
                int sm3 = LM[3];
                int sm2 = max(LM[2], sm3);
                int sm1 = max(LM[1], sm2);
                int colL0 = max(LP[0], sm1);
                int colL1 = max(qp1, sm2);
                int colL2 = max(qp2, sm3);
                int colL3 = qp3;
                // colR(ci) = min( RM[cc] for cc<ci, RP[cc] for cc>=ci )
                int sp2 = min(RP[2], RP[3]);
                int sp1 = min(RP[1], sp2);
                int sp0 = min(RP[0], sp1);
                int pm0 = RM[0];
                int pm1 = min(pm0, RM[1]);
                int pm2 = min(pm1, RM[2]);
                int colR0 = sp0;
                int colR1 = min(pm0, sp1);
                int colR2 = min(pm1, sp2);
                int colR3 = min(pm2, RP[3]);

                int p0 = lane * 4;
                int d0 = min(min(p0 - colL0, colR0 - p0), 512);        // cap = BIG
                int d1 = min(min(p0 + 1 - colL1, colR1 - p0 - 1), 512);
                int d2 = min(min(p0 + 2 - colL2, colR2 - p0 - 2), 512);
                int d3 = min(min(p0 + 3 - colL3, colR3 - p0 - 3), 512);
                float f0 = (float)d0, f1 = (float)d1, f2 = (float)d2, f3 = (float)d3;
                res.x = f0 * f0; res.y = f1 * f1; res.z = f2 * f2; res.w = f3 * f3;
            } else {
                res.x = PADV; res.y = PADV; res.z = PADV; res.w = PADV;
            }
            ((float4*)(tile + ti * 260))[lane] = res;   // balanced 8 words/bank
        }
    }
    __syncthreads();

    // ---- phase B: one column per thread, +-16 window min-plus --------------
    int c = tid;                        // column 0..255
    float lo[16], own[16], hi[16];
    #pragma unroll
    for (int i = 0; i < 16; ++i) {
        lo[i] = tile[i * 260 + c];            // rows r0-16..r0-1
        own[i] = tile[(16 + i) * 260 + c];    // rows r0..r0+15
        hi[i] = tile[(32 + i) * 260 + c];     // rows r0+16..r0+31
    }

    float dmin[16];
    #pragma unroll
    for (int k = 0; k < 16; ++k) dmin[k] = own[k];
    #pragma unroll
    for (int o = 1; o <= 16; ++o) {
        float oo = (float)(o * o);
        #pragma unroll
        for (int k = 0; k < 16; ++k) {
            int jm = k - o, jp = k + o;
            float a = (jm >= 0) ? own[jm] : lo[jm + 16];
            float b = (jp < 16) ? own[jp] : hi[jp - 16];
            dmin[k] = fminf(dmin[k], fminf(a, b) + oo);
        }
    }

    // exact fallback: windowed min > 288 can't certify +-16 optimality.
    // Brute-force the whole input slice (needs a 33x33 zero-free region to
    // trigger -> never taken for random masks; execz-skipped).
    #pragma unroll
    for (int k = 0; k < 16; ++k) {
        if (dmin[k] > 288.0f) {
            float best = dmin[k];
            int r = r0 + k;
            const float* sl = in + (long)slice * 65536;
            for (int rp = 0; rp < 256; ++rp) {
                float dr2 = (float)((r - rp) * (r - rp));
                for (int cp = 0; cp < 256; ++cp) {
                    if (sl[rp * 256 + cp] == 0.f) {
                        float dc = (float)(c - cp);
                        best = fminf(best, fmaf(dc, dc, dr2));
                    }
                }
            }
            dmin[k] = best;
        }
    }

    // write d2 (wave = 64 consecutive cols -> coalesced) + slab max
    float* dst = d2out + (long)slice * 65536 + c;
    float mmax = 0.f;
    #pragma unroll
    for (int k = 0; k < 16; ++k) {
        dst[(long)(r0 + k) * 256] = dmin[k];
        mmax = fmaxf(mmax, dmin[k]);
    }
    #pragma unroll
    for (int off = 32; off >= 1; off >>= 1)
        mmax = fmaxf(mmax, __shfl_down(mmax, off, 64));
    if (lane == 0) wm[wv] = mmax;
    __syncthreads();
    if (tid == 0)
        slabmax[bx] = fmaxf(fmaxf(wm[0], wm[1]), fmaxf(wm[2], wm[3]));
}

// ---------------- K3: epilogue ---------------------------------------------
// 1536 blocks = 32 per slice; each thread handles 2 float4s.
__global__ __launch_bounds__(256) void k3_final(float* __restrict__ out,
                                                const float* __restrict__ slabmax) {
    __shared__ float sMx;
    int tid = threadIdx.x;
    int slice = blockIdx.x >> 5;          // 32 blocks per slice
    if (tid < 16) {
        float v = slabmax[slice * 16 + tid];
        #pragma unroll
        for (int off = 8; off >= 1; off >>= 1) v = fmaxf(v, __shfl_down(v, off, 64));
        if (tid == 0) sMx = v;
    }
    __syncthreads();

    int ch = slice % 3;
    float wgt = (ch == 0) ? 0.5f : ((ch == 1) ? 1.0f : 2.0f);
    float mx = wgt * __builtin_sqrtf(sMx);

    int idx4 = blockIdx.x * 512 + tid;    // float4 index; this + idx4+256
    float4* o4 = (float4*)out;
    #pragma unroll
    for (int rep = 0; rep < 2; ++rep) {
        int i4 = idx4 + rep * 256;
        float4 d2 = o4[i4];
        float4 r;
        if (mx > 0.f) {
            float inv = 1.0f / mx;
            r.x = (mx - wgt * __builtin_sqrtf(d2.x)) * inv;
            r.y = (mx - wgt * __builtin_sqrtf(d2.y)) * inv;
            r.z = (mx - wgt * __builtin_sqrtf(d2.z)) * inv;
            r.w = (mx - wgt * __builtin_sqrtf(d2.w)) * inv;
        } else {
            r.x = wgt * __builtin_sqrtf(d2.x);
            r.y = wgt * __builtin_sqrtf(d2.y);
            r.z = wgt * __builtin_sqrtf(d2.z);
            r.w = wgt * __builtin_sqrtf(d2.w);
        }
        o4[i4] = r;
    }
}

extern "C" void kernel_launch(void* const* d_in, const int* in_sizes, int n_in,
                              void* d_out, int out_size, void* d_ws, size_t ws_size,
                              hipStream_t stream) {
    const float* in = (const float*)d_in[0];
    float* out = (float*)d_out;
    float* slabmax = (float*)d_ws;                                    // 768 floats

    kfused<<<768, 256, 0, stream>>>(in, out, slabmax);    // self-contained slabs
    k3_final<<<1536, 256, 0, stream>>>(out, slabmax);     // 2 float4 / thread
}

// Round 11
// 79.970 us; speedup vs baseline: 1.0761x; 1.0761x over previous
//
#include <hip/hip_runtime.h>

// B=16, C=3, H=256, W=256 fp32. 48 slices of 256x256.
// out = inverted, per-slice max-normalized, per-channel-weighted exact EDT.
//
// Pipeline (3 launches; kernel boundaries are the ONLY global sync — measured
// on MI355X: atomic-spin barrier ~50us, cooperative grid.sync ~120us,
// kernel boundary ~5us):
//   K1: wave per row. Ballots give every lane the full 256-col zero-mask in
//       4 ulls; each lane computes EXACT 1D nearest-zero distance for its 4
//       cols fully in registers (compile-time residue unroll + prefix
//       max/min), writes g as u16 row-major (6.3 MB, coalesced). No LDS.
//   K2: block = 16 cols x 128 rows (half-slice strip), 1536 blocks -> 6
//       waves/SIMD. Loads g strip (+-16-row halo) -> LDS (col-major, d^2 as
//       float, stride 161), one barrier, then +-16 window min-plus from
//       registers (own 8 rows + 32 halo reads). Per-pixel EXACT fallback
//       (full 256-row column scan from global g) when windowed min > 288
//       (|o|>=17 candidates are >= 289). Writes d2 -> out, block max -> ws.
//   K3: epilogue out = (mx - w*sqrt(d2))/mx; slice max = max of 32 blk maxes.

#define PADV 1e30f

// ---------------- K1: register 1D EDT via ballots ---------------------------
// Lane l holds cols 4l..4l+3. b[cc] bit j = (col 4j+cc == 0).
// Left target for col p=4l+ci, residue cc: j <= l - (ci<cc); right: j >= l + (ci>cc).
__global__ __launch_bounds__(256) void k1_g16(const float* __restrict__ in,
                                              unsigned short* __restrict__ g) {
    int row = blockIdx.x * 4 + (threadIdx.x >> 6);
    int lane = threadIdx.x & 63;
    const float4 m = ((const float4*)in)[(long)row * 64 + lane];

    unsigned long long b[4];
    b[0] = __ballot(m.x == 0.f);
    b[1] = __ballot(m.y == 0.f);
    b[2] = __ballot(m.z == 0.f);
    b[3] = __ballot(m.w == 0.f);

    unsigned long long loP = ~0ull >> (63 - lane);  // bits 0..lane
    unsigned long long loM = loP >> 1;              // bits 0..lane-1 (0 if lane==0)
    unsigned long long hiP = ~0ull << lane;         // bits lane..63
    unsigned long long hiM = hiP << 1;              // bits lane+1..63 (0 if lane==63)

    int LP[4], LM[4], RP[4], RM[4];
    #pragma unroll
    for (int cc = 0; cc < 4; ++cc) {
        unsigned long long mlp = b[cc] & loP;
        unsigned long long mlm = b[cc] & loM;
        unsigned long long mhp = b[cc] & hiP;
        unsigned long long mhm = b[cc] & hiM;
        LP[cc] = mlp ? 4 * (63 - __builtin_clzll(mlp)) + cc : -1000;  // nearest-left zero col
        LM[cc] = mlm ? 4 * (63 - __builtin_clzll(mlm)) + cc : -1000;
        RP[cc] = mhp ? 4 * __builtin_ctzll(mhp) + cc : 2000;          // nearest-right zero col
        RM[cc] = mhm ? 4 * __builtin_ctzll(mhm) + cc : 2000;
    }
    // colL(ci) = max( LP[cc] for cc<=ci, LM[cc] for cc>ci )
    int qp1 = max(LP[0], LP[1]);
    int qp2 = max(qp1, LP[2]);
    int qp3 = max(qp2, LP[3]);
    int sm3 = LM[3];
    int sm2 = max(LM[2], sm3);
    int sm1 = max(LM[1], sm2);
    int colL0 = max(LP[0], sm1);
    int colL1 = max(qp1, sm2);
    int colL2 = max(qp2, sm3);
    int colL3 = qp3;
    // colR(ci) = min( RM[cc] for cc<ci, RP[cc] for cc>=ci )
    int sp2 = min(RP[2], RP[3]);
    int sp1 = min(RP[1], sp2);
    int sp0 = min(RP[0], sp1);
    int pm0 = RM[0];
    int pm1 = min(pm0, RM[1]);
    int pm2 = min(pm1, RM[2]);
    int colR0 = sp0;
    int colR1 = min(pm0, sp1);
    int colR2 = min(pm1, sp2);
    int colR3 = min(pm2, RP[3]);

    int p0 = lane * 4;
    int d0 = min(min(p0 - colL0, colR0 - p0), 512);          // cap = BIG = H+W
    int d1 = min(min(p0 + 1 - colL1, colR1 - p0 - 1), 512);
    int d2 = min(min(p0 + 2 - colL2, colR2 - p0 - 2), 512);
    int d3 = min(min(p0 + 3 - colL3, colR3 - p0 - 3), 512);

    ushort4 v;
    v.x = (unsigned short)d0; v.y = (unsigned short)d1;
    v.z = (unsigned short)d2; v.w = (unsigned short)d3;
    ((ushort4*)(g + (long)row * 256))[lane] = v;             // coalesced 512 B/wave
}

// ---------------- K2: column min-plus over g --------------------------------
// Grid 1536 = 48 slices x 16 col-strips x 2 row-halves. 256 threads:
// c = tid&15 (column), rg = tid>>4 (8-row group). LDS tile: [16 cols][161]
// (160 rows = 128 owned + 16 halo each side; stride 161 -> 2-way max banking).
__global__ __launch_bounds__(256) __attribute__((amdgpu_waves_per_eu(4)))
void k2_colpass(const unsigned short* __restrict__ g,
                float* __restrict__ d2out,
                float* __restrict__ stripmax) {
    __shared__ float tile[16 * 161];   // 10304 B
    __shared__ float wm[4];
    int bx = blockIdx.x;
    int slice = bx >> 5;
    int sub = bx & 31;
    int strip = sub >> 1;
    int half = sub & 1;                // adjacent blocks share a strip (L2 reuse)
    int w0 = strip * 16;
    int base = half * 128;
    int tid = threadIdx.x;

    // fill tile rows [base-16, base+143]; u16 d -> float d^2 on the fly
    if (tid < 160) {
        int r = base - 16 + tid;
        if (r >= 0 && r < 256) {
            const uint4* src = (const uint4*)(g + (long)slice * 65536 + (long)r * 256 + w0);
            #pragma unroll
            for (int j = 0; j < 2; ++j) {
                uint4 q = src[j];
                unsigned vv[4] = {q.x, q.y, q.z, q.w};
                #pragma unroll
                for (int e = 0; e < 4; ++e) {
                    float dl = (float)(vv[e] & 0xffffu);
                    float dh = (float)(vv[e] >> 16);
                    int col = j * 8 + e * 2;
                    tile[col * 161 + tid] = dl * dl;         // bank (col+tid)%32: 2-way
                    tile[(col + 1) * 161 + tid] = dh * dh;
                }
            }
        } else {
            #pragma unroll
            for (int cc = 0; cc < 16; ++cc) tile[cc * 161 + tid] = PADV;
        }
    }
    __syncthreads();

    int c = tid & 15;
    int rg = tid >> 4;
    int i0 = 16 + rg * 8;              // tile index of first owned row
    float own[8], lo[16], hi[16];
    #pragma unroll
    for (int k = 0; k < 8; ++k) own[k] = tile[c * 161 + i0 + k];
    #pragma unroll
    for (int i = 0; i < 16; ++i) {
        lo[i] = tile[c * 161 + i0 - 16 + i];   // rows r0-16..r0-1
        hi[i] = tile[c * 161 + i0 + 8 + i];    // rows r0+8..r0+23
    }

    // window min-plus, +-o paired, all indices compile-time
    float dmin[8];
    #pragma unroll
    for (int k = 0; k < 8; ++k) dmin[k] = own[k];
    #pragma unroll
    for (int o = 1; o <= 16; ++o) {
        float oo = (float)(o * o);
        #pragma unroll
        for (int k = 0; k < 8; ++k) {
            int jm = k - o, jp = k + o;
            float a = (jm >= 0) ? own[jm] : lo[jm + 16];
            float b = (jp < 8) ? own[jp] : hi[jp - 8];
            dmin[k] = fminf(dmin[k], fminf(a, b) + oo);
        }
    }

    int p = w0 + c;
    int r0 = base + rg * 8;
    // exact fallback: windowed min > 288 can't certify +-16 optimality; rescan
    // the full column from global g. Never taken for random masks (execz).
    #pragma unroll
    for (int k = 0; k < 8; ++k) {
        if (dmin[k] > 288.0f) {
            float best = dmin[k];
            int r = r0 + k;
            const unsigned short* col = g + (long)slice * 65536 + p;
            for (int rp = 0; rp < 256; ++rp) {
                float gv = (float)col[rp * 256];
                float dr = (float)(r - rp);
                best = fminf(best, fmaf(dr, dr, gv * gv));
            }
            dmin[k] = best;
        }
    }

    // write d2 + block max
    float* dst = d2out + (long)slice * 65536 + w0 + c;
    float mmax = 0.f;
    #pragma unroll
    for (int k = 0; k < 8; ++k) {
        dst[(long)(r0 + k) * 256] = dmin[k];
        mmax = fmaxf(mmax, dmin[k]);
    }
    #pragma unroll
    for (int off = 32; off >= 1; off >>= 1)
        mmax = fmaxf(mmax, __shfl_down(mmax, off, 64));
    if ((tid & 63) == 0) wm[tid >> 6] = mmax;
    __syncthreads();
    if (tid == 0)
        stripmax[bx] = fmaxf(fmaxf(wm[0], wm[1]), fmaxf(wm[2], wm[3]));
}

// ---------------- K3: epilogue ---------------------------------------------
// 64 blocks per slice; each block reduces the slice's 32 block maxes once.
__global__ __launch_bounds__(256) void k3_final(float* __restrict__ out,
                                                const float* __restrict__ stripmax) {
    __shared__ float sMx;
    int tid = threadIdx.x;
    int idx4 = blockIdx.x * 256 + tid;    // float4 index, 786432 total
    int slice = blockIdx.x >> 6;          // 64 blocks per slice
    if (tid < 32) {
        float v = stripmax[slice * 32 + tid];
        #pragma unroll
        for (int off = 16; off >= 1; off >>= 1) v = fmaxf(v, __shfl_down(v, off, 64));
        if (tid == 0) sMx = v;
    }
    __syncthreads();

    int c = slice % 3;
    float wgt = (c == 0) ? 0.5f : ((c == 1) ? 1.0f : 2.0f);
    float mx = wgt * __builtin_sqrtf(sMx);

    float4 d2 = ((float4*)out)[idx4];
    float4 r;
    if (mx > 0.f) {
        float inv = 1.0f / mx;
        r.x = (mx - wgt * __builtin_sqrtf(d2.x)) * inv;
        r.y = (mx - wgt * __builtin_sqrtf(d2.y)) * inv;
        r.z = (mx - wgt * __builtin_sqrtf(d2.z)) * inv;
        r.w = (mx - wgt * __builtin_sqrtf(d2.w)) * inv;
    } else {
        r.x = wgt * __builtin_sqrtf(d2.x);
        r.y = wgt * __builtin_sqrtf(d2.y);
        r.z = wgt * __builtin_sqrtf(d2.z);
        r.w = wgt * __builtin_sqrtf(d2.w);
    }
    ((float4*)out)[idx4] = r;
}

extern "C" void kernel_launch(void* const* d_in, const int* in_sizes, int n_in,
                              void* d_out, int out_size, void* d_ws, size_t ws_size,
                              hipStream_t stream) {
    const float* in = (const float*)d_in[0];
    float* out = (float*)d_out;
    float* stripmax = (float*)d_ws;                                   // 1536 floats
    unsigned short* g = (unsigned short*)((char*)d_ws + 8192);        // 6.29 MB

    k1_g16<<<3072, 256, 0, stream>>>(in, g);              // 12288 rows, wave/row
    k2_colpass<<<1536, 256, 0, stream>>>(g, out, stripmax);
    k3_final<<<3072, 256, 0, stream>>>(out, stripmax);    // 786432 float4
}